// Round 3
// baseline (99847.583 us; speedup 1.0000x reference)
//
#include <hip/hip_runtime.h>
#include <hip/hip_cooperative_groups.h>
#include <math.h>

namespace cg = cooperative_groups;

#define D 128
#define NH 16
#define HD 8
#define NLAYER 16
#define V 17
#define L 1024
#define BOSX 16
#define NHEAL 31
#define NWG 128

struct P {
  const int* tokens;
  const float *emb, *pos, *ln1_s, *ln1_b, *wqkv, *bqkv, *wo, *bo;
  const float *ln2_s, *ln2_b, *w1, *b1, *w2, *b2, *lnf_s, *lnf_b, *hw, *hb;
  float *h, *qbuf, *kc, *vc, *ll_;
  int *lat, *heal_row, *bounds;
  float *logits, *out_tok;
};

__device__ __forceinline__ float geluf(float a) {
  float cgv = 0.7978845608028654f * (a + 0.044715f * a * a * a);
  cgv = fminf(fmaxf(cgv, -15.f), 15.f);
  float e = __expf(2.f * cgv);
  return 0.5f * a * (1.f + (e - 1.f) / (e + 1.f));
}

// LayerNorm of in[0..127] -> out[0..127]; 256 threads; trailing barrier.
__device__ void lnorm(const float* __restrict__ s, const float* __restrict__ b,
                      const float* in, float* out, float* red) {
  int t = threadIdx.x;
  float v = (t < D) ? in[t] : 0.f;
  float sm = v;
#pragma unroll
  for (int o = 32; o; o >>= 1) sm += __shfl_xor(sm, o, 64);
  if ((t & 63) == 0) red[t >> 6] = sm;
  __syncthreads();
  float mean = (red[0] + red[1] + red[2] + red[3]) * (1.f / 128.f);
  float d = (t < D) ? (v - mean) : 0.f;
  float vs = d * d;
#pragma unroll
  for (int o = 32; o; o >>= 1) vs += __shfl_xor(vs, o, 64);
  if ((t & 63) == 0) red[4 + (t >> 6)] = vs;
  __syncthreads();
  float rstd = rsqrtf((red[4] + red[5] + red[6] + red[7]) * (1.f / 128.f) + 1e-5f);
  if (t < D) out[t] = d * rstd * s[t] + b[t];
  __syncthreads();
}

// qkv = x @ w[128x384] + b for one row; threads 0..191 take cols (t, t+192)
__device__ void qkvRow(const float* __restrict__ w, const float* __restrict__ b,
                       int row, float* q, float* k, float* v, const float* x) {
  int t = threadIdx.x;
  if (t < 192) {
    int c0 = t, c1 = t + 192;
    const float* w0 = w + c0;
    const float* w1 = w + c1;
    float a0 = 0.f, a1 = 0.f;
#pragma unroll 8
    for (int d = 0; d < D; ++d) {
      float xv = x[d];
      a0 += xv * w0[d * 384];
      a1 += xv * w1[d * 384];
    }
    a0 += b[c0]; a1 += b[c1];
    if (c0 < 128) q[row * D + c0] = a0;
    else          k[row * D + (c0 - 128)] = a0;
    if (c1 < 256) k[row * D + (c1 - 128)] = a1;
    else          v[row * D + (c1 - 256)] = a1;
  }
}

// embed + LN1 + qkv(layer 0) for one row
__device__ void rowPre(int row, const P& p, float* hrowS, float* xS, float* redS) {
  int t = threadIdx.x;
  if (t < D) {
    float hv = p.emb[p.lat[row] * D + t] + p.pos[row * D + t];
    p.h[row * D + t] = hv;
    hrowS[t] = hv;
  }
  __syncthreads();
  lnorm(p.ln1_s, p.ln1_b, hrowS, xS, redS);
  qkvRow(p.wqkv, p.bqkv, row, p.qbuf, p.kc, p.vc, xS);
}

// attention(l)+proj+res+LN2+FFN+res; then LN1+qkv(l+1) or LNf+head
__device__ void rowMain(int row, int l, const P& p, float* hrowS, float* xS,
                        float* obufS, float* fS, float* padS, float* redS) {
  int t = threadIdx.x;
  if (t < D) hrowS[t] = p.h[row * D + t];
  // ---- attention: (head = t>>4, lane = t&15), softmax without max-sub (scores tiny)
  {
    const float* kcl = p.kc + (size_t)l * L * D;
    const float* vcl = p.vc + (size_t)l * L * D;
    int head = t >> 4, lane = t & 15;
    const float4* qp = (const float4*)(p.qbuf + row * D + head * HD);
    float4 q0 = qp[0], q1 = qp[1];
    float sum = 0.f;
    float a0=0,a1=0,a2=0,a3=0,a4=0,a5=0,a6=0,a7=0;
    for (int key = lane; key <= row; key += 16) {
      const float4* kp = (const float4*)(kcl + key * D + head * HD);
      float4 k0 = kp[0], k1 = kp[1];
      float sc = q0.x*k0.x + q0.y*k0.y + q0.z*k0.z + q0.w*k0.w
               + q1.x*k1.x + q1.y*k1.y + q1.z*k1.z + q1.w*k1.w;
      float pr = __expf(sc * 0.35355339059327376f);
      const float4* vp = (const float4*)(vcl + key * D + head * HD);
      float4 v0 = vp[0], v1 = vp[1];
      sum += pr;
      a0 += pr*v0.x; a1 += pr*v0.y; a2 += pr*v0.z; a3 += pr*v0.w;
      a4 += pr*v1.x; a5 += pr*v1.y; a6 += pr*v1.z; a7 += pr*v1.w;
    }
#pragma unroll
    for (int o = 1; o < 16; o <<= 1) {
      sum += __shfl_xor(sum, o, 16);
      a0 += __shfl_xor(a0, o, 16); a1 += __shfl_xor(a1, o, 16);
      a2 += __shfl_xor(a2, o, 16); a3 += __shfl_xor(a3, o, 16);
      a4 += __shfl_xor(a4, o, 16); a5 += __shfl_xor(a5, o, 16);
      a6 += __shfl_xor(a6, o, 16); a7 += __shfl_xor(a7, o, 16);
    }
    if (lane == 0) {
      float inv = 1.f / sum;
      obufS[head * HD + 0] = a0 * inv; obufS[head * HD + 1] = a1 * inv;
      obufS[head * HD + 2] = a2 * inv; obufS[head * HD + 3] = a3 * inv;
      obufS[head * HD + 4] = a4 * inv; obufS[head * HD + 5] = a5 * inv;
      obufS[head * HD + 6] = a6 * inv; obufS[head * HD + 7] = a7 * inv;
    }
  }
  __syncthreads();
  // ---- proj (split-d over 2 halves) + residual ----
  {
    int half = t >> 7, c = t & 127;
    const float* wp = p.wo + (size_t)l * D * D + c;
    float acc = 0.f;
    int d0 = half * 64;
#pragma unroll 8
    for (int d = d0; d < d0 + 64; ++d) acc += obufS[d] * wp[d * D];
    padS[half * 128 + c] = acc;
  }
  __syncthreads();
  if (t < D) {
    float hv = hrowS[t] + padS[t] + padS[128 + t] + p.bo[l * D + t];
    hrowS[t] = hv;
    p.h[row * D + t] = hv;
  }
  __syncthreads();
  lnorm(p.ln2_s + l * D, p.ln2_b + l * D, hrowS, xS, redS);
  // ---- FF1 + gelu: cols (t, t+256) ----
  {
    const float* w1p = p.w1 + (size_t)l * D * 512;
    float acc0 = 0.f, acc1 = 0.f;
#pragma unroll 8
    for (int d = 0; d < D; ++d) {
      float xv = xS[d];
      acc0 += xv * w1p[d * 512 + t];
      acc1 += xv * w1p[d * 512 + t + 256];
    }
    fS[t]       = geluf(acc0 + p.b1[l * 512 + t]);
    fS[t + 256] = geluf(acc1 + p.b1[l * 512 + t + 256]);
  }
  __syncthreads();
  // ---- FF2 (split-d over 2 halves of 256) + residual ----
  {
    int half = t >> 7, c = t & 127;
    const float* w2p = p.w2 + (size_t)l * 512 * D + c;
    float acc = 0.f;
    int d0 = half * 256;
#pragma unroll 8
    for (int d = d0; d < d0 + 256; ++d) acc += fS[d] * w2p[d * D];
    padS[half * 128 + c] = acc;
  }
  __syncthreads();
  if (t < D) {
    float hv = hrowS[t] + padS[t] + padS[128 + t] + p.b2[l * D + t];
    hrowS[t] = hv;
    p.h[row * D + t] = hv;
  }
  __syncthreads();
  if (l < NLAYER - 1) {
    lnorm(p.ln1_s + (l + 1) * D, p.ln1_b + (l + 1) * D, hrowS, xS, redS);
    qkvRow(p.wqkv + (size_t)(l + 1) * D * 384, p.bqkv + (l + 1) * 384, row,
           p.qbuf, p.kc + (size_t)(l + 1) * L * D, p.vc + (size_t)(l + 1) * L * D, xS);
  } else {
    lnorm(p.lnf_s, p.lnf_b, hrowS, xS, redS);
    if (t < V * 8) {
      int col = t >> 3, seg = t & 7;
      float acc = 0.f;
      int d0 = seg * 16;
#pragma unroll
      for (int d = d0; d < d0 + 16; ++d) acc += xS[d] * p.hw[d * V + col];
      padS[t] = acc;
    }
    __syncthreads();
    if (t < V) {
      float a = padS[t*8] + padS[t*8+1] + padS[t*8+2] + padS[t*8+3]
              + padS[t*8+4] + padS[t*8+5] + padS[t*8+6] + padS[t*8+7];
      p.logits[row * V + t] = a + p.hb[t];
    }
    __syncthreads();
  }
}

__global__ void kMega(P p) {
  cg::grid_group grid = cg::this_grid();
  __shared__ float hrowS[D];
  __shared__ float xS[D];
  __shared__ float obufS[D];
  __shared__ float fS[512];
  __shared__ float padS[256];
  __shared__ float redS[8];
  __shared__ float sortS[L];
  __shared__ int cntS[257];
  int wg = blockIdx.x, t = threadIdx.x;
  int gid = wg * 256 + t;

  // ---- init lat ----
  if (gid == 0) p.lat[0] = BOSX;
  if (gid < L) p.lat[gid + 1] = p.tokens[gid];
  grid.sync();

  // ---- phase A: full pass over 1024 rows ----
  for (int row = wg; row < L; row += NWG) rowPre(row, p, hrowS, xS, redS);
  grid.sync();
  for (int l = 0; l < NLAYER; ++l) {
    for (int row = wg; row < L; row += NWG)
      rowMain(row, l, p, hrowS, xS, obufS, fS, padS, redS);
    grid.sync();
  }

  // ---- log-likelihoods ----
  if (gid < L) {
    const float* r = p.logits + gid * V;
    float m = r[0];
#pragma unroll
    for (int v = 1; v < V; ++v) m = fmaxf(m, r[v]);
    float s = 0.f;
#pragma unroll
    for (int v = 0; v < V; ++v) s += expf(r[v] - m);
    p.ll_[gid] = r[p.lat[gid + 1]] - (m + logf(s));
  }
  grid.sync();

  // ---- sort + quantile + heal list + bounds + heal 0 (WG 0 only) ----
  if (wg == 0) {
    for (int i = t; i < L; i += 256) sortS[i] = p.ll_[i];
    __syncthreads();
    for (int ksz = 2; ksz <= L; ksz <<= 1) {
      for (int j = ksz >> 1; j; j >>= 1) {
        for (int i = t; i < L; i += 256) {
          int l2 = i ^ j;
          if (l2 > i) {
            bool up = ((i & ksz) == 0);
            float a = sortS[i], b = sortS[l2];
            if ((a > b) == up) { sortS[i] = b; sortS[l2] = a; }
          }
        }
        __syncthreads();
      }
    }
    if (t == 0) {
      double frac = 0.03 * 1023.0 - 30.0;  // 0.69
      redS[0] = (float)((double)sortS[30] + frac * ((double)sortS[31] - (double)sortS[30]));
    }
    __syncthreads();
    float val = redS[0];
    // masked positions, ordered: thread t owns positions 4t..4t+3
    float lv[4];
    int loc[4], cnt = 0;
#pragma unroll
    for (int j = 0; j < 4; ++j) lv[j] = p.ll_[t * 4 + j];
#pragma unroll
    for (int j = 0; j < 4; ++j)
      if (lv[j] < val) loc[cnt++] = t * 4 + j;
    cntS[t] = cnt;
    __syncthreads();
    if (t == 0) {
      int run = 0;
      for (int i = 0; i < 256; ++i) { int c = cntS[i]; cntS[i] = run; run += c; }
      cntS[256] = run;
    }
    __syncthreads();
    int base = cntS[t];
    for (int j = 0; j < cnt; ++j)
      if (base + j < NHEAL) p.heal_row[base + j] = loc[j];
    __syncthreads();
    if (t == 0) {
      int c = cntS[256];
      if (c > NHEAL) c = NHEAL;
      for (int k = 0; k < NHEAL; ++k) {
        if (k < c) {
          p.bounds[2 * k] = (k == 0) ? 1 : (p.heal_row[k - 1] + 1);
          p.bounds[2 * k + 1] = (k == 0) ? 0 : p.heal_row[k];
        } else {
          p.heal_row[k] = -1;
          p.bounds[2 * k] = 1;
          p.bounds[2 * k + 1] = 0;
        }
      }
      p.bounds[2 * NHEAL] = (c > 0) ? (p.heal_row[c - 1] + 1) : L;
      p.bounds[2 * NHEAL + 1] = L - 1;
      // heal 0 from phase-A logits
      if (c > 0) {
        int r = p.heal_row[0];
        const float* rowp = p.logits + r * V;
        int best = 0; float bv = rowp[0];
        for (int v = 1; v < BOSX; ++v)
          if (rowp[v] > bv) { bv = rowp[v]; best = v; }
        p.lat[r + 1] = best;
      }
    }
  }
  grid.sync();

  // ---- chunks 1..30 (heal) and NHEAL (tail, no heal) ----
  for (int k = 1; k <= NHEAL; ++k) {
    int cs = p.bounds[2 * k], ce = p.bounds[2 * k + 1];
    if (cs <= ce) {
      for (int row = cs + wg; row <= ce; row += NWG) rowPre(row, p, hrowS, xS, redS);
      grid.sync();
      for (int l = 0; l < NLAYER; ++l) {
        for (int row = cs + wg; row <= ce; row += NWG)
          rowMain(row, l, p, hrowS, xS, obufS, fS, padS, redS);
        grid.sync();
      }
      if (k < NHEAL && wg == 0 && t == 0) {
        int r = p.heal_row[k];
        if (r >= 0) {
          const float* rowp = p.logits + r * V;
          int best = 0; float bv = rowp[0];
          for (int v = 1; v < BOSX; ++v)
            if (rowp[v] > bv) { bv = rowp[v]; best = v; }
          p.lat[r + 1] = best;
        }
      }
      grid.sync();
    }
  }

  // ---- tokens out ----
  if (gid < L) p.out_tok[gid] = (float)p.lat[gid + 1];
}

extern "C" void kernel_launch(void* const* d_in, const int* in_sizes, int n_in,
                              void* d_out, int out_size, void* d_ws, size_t ws_size,
                              hipStream_t stream) {
  P prm;
  prm.tokens = (const int*)d_in[0];
  prm.emb    = (const float*)d_in[1];
  prm.pos    = (const float*)d_in[2];
  prm.ln1_s  = (const float*)d_in[3];
  prm.ln1_b  = (const float*)d_in[4];
  prm.wqkv   = (const float*)d_in[5];
  prm.bqkv   = (const float*)d_in[6];
  prm.wo     = (const float*)d_in[7];
  prm.bo     = (const float*)d_in[8];
  prm.ln2_s  = (const float*)d_in[9];
  prm.ln2_b  = (const float*)d_in[10];
  prm.w1     = (const float*)d_in[11];
  prm.b1     = (const float*)d_in[12];
  prm.w2     = (const float*)d_in[13];
  prm.b2     = (const float*)d_in[14];
  prm.lnf_s  = (const float*)d_in[15];
  prm.lnf_b  = (const float*)d_in[16];
  prm.hw     = (const float*)d_in[17];
  prm.hb     = (const float*)d_in[18];

  float* ws = (float*)d_ws;
  prm.h    = ws;                       // L*D
  prm.qbuf = prm.h + L * D;            // L*D
  prm.kc   = prm.qbuf + L * D;         // NLAYER*L*D
  prm.vc   = prm.kc + NLAYER * L * D;  // NLAYER*L*D
  prm.ll_  = prm.vc + NLAYER * L * D;  // L
  prm.lat      = (int*)(prm.ll_ + L);  // 1025 (pad 1032)
  prm.heal_row = prm.lat + 1032;       // 32
  prm.bounds   = prm.heal_row + 32;    // 64

  prm.logits  = (float*)d_out;         // L*V
  prm.out_tok = prm.logits + L * V;    // L

  void* args[] = { &prm };
  hipLaunchCooperativeKernel((const void*)kMega, dim3(NWG), dim3(256), args, 0, stream);
}